// Round 5
// baseline (756.771 us; speedup 1.0000x reference)
//
#include <hip/hip_runtime.h>

typedef __bf16 bf16x8 __attribute__((ext_vector_type(8)));
typedef float  floatx4 __attribute__((ext_vector_type(4)));

constexpr int B_    = 2048;
constexpr int NIN   = 256;
constexpr int H_    = 128;
constexpr int RANK_ = 8;
constexpr float EPS_ = 1e-5f;
constexpr int NBLK  = 512;          // 2 blocks/CU
constexpr int MT    = 32;           // rows per block
constexpr int SZS   = 36;           // sZin stride (floats), 16B-aligned rows

// Monotonic-counter grid barrier. 512 blocks guaranteed co-resident via
// __launch_bounds__(256,2): LDS 19.5KB (<80KB/2), VGPR<=256.
__device__ __forceinline__ void gsync(unsigned* cnt, unsigned target) {
    __syncthreads();
    if (threadIdx.x == 0) {
        __threadfence();
        atomicAdd(cnt, 1u);
        while (__hip_atomic_load(cnt, __ATOMIC_ACQUIRE, __HIP_MEMORY_SCOPE_AGENT) < target)
            __builtin_amdgcn_s_sleep(4);
        __threadfence();
    }
    __syncthreads();
}

__global__ __launch_bounds__(256, 2)
void k_mega(const float* __restrict__ X,  const float* __restrict__ W1, const float* __restrict__ b1,
            const float* __restrict__ W2, const float* __restrict__ b2,
            const float* __restrict__ W3, const float* __restrict__ b3,
            const float* __restrict__ P,  const float* __restrict__ gz, const float* __restrict__ bz,
            const float* __restrict__ gy, const float* __restrict__ by,
            float* __restrict__ out, unsigned* __restrict__ cnt,
            float* __restrict__ Z, float* __restrict__ R2,
            float* __restrict__ sums, float* __restrict__ ysums,
            float* __restrict__ T, __bf16* __restrict__ Zbf, __bf16* __restrict__ Pperm)
{
    __shared__ float smem[4864];     // 19,456 B
    const int bx = blockIdx.x, t = threadIdx.x;
    unsigned btgt = 0;

    // ===== phase 0: zero stats, in_proj (4 rows/blk), pconv (2 units/blk) =====
    if (bx < RANK_)       sums[bx * 256 + t] = 0.f;
    else if (bx == RANK_) ysums[t] = 0.f;

    {
        const int col = t & 127, half = t >> 7;
        for (int it = 0; it < 2; ++it) {
            const int row0 = bx * 4 + it * 2;
            smem[t]       = X[(size_t)row0       * NIN + t];
            smem[256 + t] = X[(size_t)(row0 + 1) * NIN + t];
            __syncthreads();
            float s1 = 0.f, s2 = 0.f;
            const float* sx = smem + half * 256;
#pragma unroll 8
            for (int i = 0; i < NIN; ++i) {
                s1 = fmaf(sx[i], W1[i * H_ + col], s1);
                s2 = fmaf(sx[i], W2[i * H_ + col], s2);
            }
            const int b = row0 + half;
            const float z = fmaxf(s1 + b1[col], 0.f);
            const float r = fmaxf(s2 + b2[col], 0.f);
            Z[(size_t)b * H_ + col]   = z;
            Zbf[(size_t)b * H_ + col] = (__bf16)z;
            R2[(size_t)b * H_ + col]  = r;
            __syncthreads();
        }
    }
    {
        const int s = t >> 6, Lp = t & 63, quad = Lp >> 4, lo = Lp & 15;
        for (int j = 0; j < 2; ++j) {
            const int u = bx * 2 + j, pr = u >> 7, p = u & 127;
            const float* Pp = P     + ((size_t)pr * H_ + p) * (H_ * H_);
            __bf16*      dp = Pperm + ((size_t)pr * H_ + p) * (H_ * H_);
#pragma unroll
            for (int c = 0; c < 8; ++c) {
                __bf16 v[8];
#pragma unroll
                for (int jj = 0; jj < 8; ++jj)
                    v[jj] = (__bf16)Pp[(s * 32 + quad * 8 + jj) * H_ + c * 16 + lo];
                *(bf16x8*)(dp + (((size_t)(s * 8 + c)) * 64 + Lp) * 8) = *(const bf16x8*)v;
            }
        }
    }
    btgt += NBLK; gsync(cnt, btgt);

    // ===== rank loop =====
    const int m = bx >> 3, kg = bx & 7, b0 = m * MT;
    const int w = t >> 6, L = t & 63, quad = L >> 4, lo = L & 15;
    const int sp = t & 127, rg = t >> 7;      // staging: col, row-parity

    // A-frags: rank-invariant Z rows
    bf16x8 A[2][4];
#pragma unroll
    for (int mt = 0; mt < 2; ++mt)
#pragma unroll
        for (int ks = 0; ks < 4; ++ks)
            A[mt][ks] = *(const bf16x8*)(Zbf + (size_t)(b0 + mt * 16 + lo) * H_ + ks * 32 + quad * 8);

    float Yacc[16];
#pragma unroll
    for (int i = 0; i < 16; ++i) Yacc[i] = 0.f;

    for (int r = 0; r < RANK_; ++r) {
        float* sAl = smem + 4608; float* sBe = smem + 4736;
        if (t < 128) {
            if (r == 0) { sAl[t] = 1.f; sBe[t] = 0.f; }
            else {
                const float s1 = sums[(r - 1) * 256 + t], s2 = sums[(r - 1) * 256 + 128 + t];
                const float mm = s1 * (1.f / B_);
                const float var = s2 * (1.f / B_) - mm * mm;
                const float a = rsqrtf(var + EPS_) * gz[t];
                sAl[t] = a; sBe[t] = bz[t] - mm * a;
            }
        }
        __syncthreads();
        {   // stage normalized Zi tile -> sZin[p][row]; fold into Yacc
            const float* prevT = (r == 0) ? Z : (T + (size_t)(r - 1) * B_ * H_);
            const float a = sAl[sp], be = sBe[sp];
#pragma unroll
            for (int i = 0; i < 16; ++i) {
                const int row = rg + 2 * i;
                const float zin = fmaf(prevT[(size_t)(b0 + row) * H_ + sp], a, be);
                smem[sp * SZS + row] = zin;
                if (r >= 1) Yacc[i] += zin;
            }
        }
        __syncthreads();

        floatx4 acc[2];
        acc[0] = (floatx4){0.f, 0.f, 0.f, 0.f};
        acc[1] = (floatx4){0.f, 0.f, 0.f, 0.f};
        const bf16x8* Pb = (const bf16x8*)(Pperm + (size_t)r * H_ * H_ * H_);
        for (int pp = 0; pp < 32; ++pp) {
            const int p = pp * 4 + w;
            bf16x8 Bf[4];
#pragma unroll
            for (int s = 0; s < 4; ++s)
                Bf[s] = Pb[((size_t)(p * 4 + s) * 8 + kg) * 64 + L];
            floatx4 S[2];
            S[0] = (floatx4){0.f, 0.f, 0.f, 0.f};
            S[1] = (floatx4){0.f, 0.f, 0.f, 0.f};
#pragma unroll
            for (int ks = 0; ks < 4; ++ks)
#pragma unroll
                for (int mt = 0; mt < 2; ++mt)
                    S[mt] = __builtin_amdgcn_mfma_f32_16x16x32_bf16(A[mt][ks], Bf[ks], S[mt], 0, 0, 0);
#pragma unroll
            for (int mt = 0; mt < 2; ++mt) {
                const floatx4 zi = *(const floatx4*)&smem[p * SZS + mt * 16 + quad * 4];
                acc[mt] += zi * S[mt];
            }
        }
        __syncthreads();                  // sZin dead; reuse for reduce
#pragma unroll
        for (int mt = 0; mt < 2; ++mt)
#pragma unroll
            for (int i = 0; i < 4; ++i)
                smem[w * 512 + (mt * 4 + i) * 64 + L] = acc[mt][i];
        if (t < 32) smem[2048 + t] = 0.f;
        __syncthreads();

        float* Tr = T + (size_t)r * B_ * H_;
        float cs = 0.f, cs2 = 0.f;
#pragma unroll
        for (int k2 = 0; k2 < 2; ++k2) {
            const int e = t + 256 * k2;
            const float v = smem[e] + smem[512 + e] + smem[1024 + e] + smem[1536 + e];
            const int j = e >> 6, L2 = e & 63;
            const int row = b0 + (j >> 2) * 16 + (L2 >> 4) * 4 + (j & 3);
            const int col = kg * 16 + (L2 & 15);
            Tr[(size_t)row * H_ + col] = v;
            cs += v; cs2 += v * v;
        }
        cs  += __shfl_xor(cs, 16);  cs  += __shfl_xor(cs, 32);
        cs2 += __shfl_xor(cs2, 16); cs2 += __shfl_xor(cs2, 32);
        if (L < 16) { atomicAdd(&smem[2048 + L], cs); atomicAdd(&smem[2064 + L], cs2); }
        __syncthreads();
        if (t < 16)      atomicAdd(&sums[r * 256 + kg * 16 + t],        smem[2048 + t]);
        else if (t < 32) atomicAdd(&sums[r * 256 + 128 + kg * 16 + t - 16], smem[2048 + t]);

        btgt += NBLK; gsync(cnt, btgt);
    }

    // ===== final: Zin_7 into Yacc, Y stats =====
    {
        float* sAl = smem + 4608; float* sBe = smem + 4736;
        if (t < 128) {
            const float s1 = sums[7 * 256 + t], s2 = sums[7 * 256 + 128 + t];
            const float mm = s1 * (1.f / B_);
            const float var = s2 * (1.f / B_) - mm * mm;
            const float a = rsqrtf(var + EPS_) * gz[t];
            sAl[t] = a; sBe[t] = bz[t] - mm * a;
        }
        if (t < 256) { smem[t] = 0.f; }
        __syncthreads();
        const float a = sAl[sp], be = sBe[sp];
        const float* T7 = T + (size_t)7 * B_ * H_;
        float ps = 0.f, ps2 = 0.f;
#pragma unroll
        for (int i = 0; i < 16; ++i) {
            const int row = rg + 2 * i;
            const float zin = fmaf(T7[(size_t)(b0 + row) * H_ + sp], a, be);
            const float y = (Yacc[i] + zin) * (1.f / RANK_);
            Yacc[i] = y;
            ps += y; ps2 += y * y;
        }
        atomicAdd(&smem[sp], ps);
        atomicAdd(&smem[128 + sp], ps2);
        __syncthreads();
        if (kg == 0 && t < 128) {
            atomicAdd(&ysums[t],       smem[t]);
            atomicAdd(&ysums[128 + t], smem[128 + t]);
        }
    }
    btgt += NBLK; gsync(cnt, btgt);

    // ===== F2: out = relu(relu(BN(Y)@W3 + b3) + R2), block cols kg*16.. =====
    {
        const float mm = ysums[sp] * (1.f / B_);
        const float var = ysums[128 + sp] * (1.f / B_) - mm * mm;
        const float ay = rsqrtf(var + EPS_) * gy[sp];
        const float bb = by[sp] - mm * ay;
#pragma unroll
        for (int i = 0; i < 16; ++i)
            smem[(rg + 2 * i) * 129 + sp] = fmaf(Yacc[i], ay, bb);
        __syncthreads();
        const int orow = t >> 4;
        const int ocol = kg * 16 + (t & 15);
        for (int rr = orow; rr < MT; rr += 16) {
            float s = 0.f;
            const float* sy = smem + rr * 129;
#pragma unroll 8
            for (int h = 0; h < H_; ++h)
                s = fmaf(sy[h], W3[h * H_ + ocol], s);
            const size_t gi = (size_t)(b0 + rr) * H_ + ocol;
            out[gi] = fmaxf(fmaxf(s + b3[ocol], 0.f) + R2[gi], 0.f);
        }
    }
}

// ---------------------------------------------------------------------------
extern "C" void kernel_launch(void* const* d_in, const int* in_sizes, int n_in,
                              void* d_out, int out_size, void* d_ws, size_t ws_size,
                              hipStream_t stream) {
    const float* X  = (const float*)d_in[0];
    const float* W1 = (const float*)d_in[1];
    const float* b1 = (const float*)d_in[2];
    const float* W2 = (const float*)d_in[3];
    const float* b2 = (const float*)d_in[4];
    const float* W3 = (const float*)d_in[5];
    const float* b3 = (const float*)d_in[6];
    const float* P  = (const float*)d_in[7];
    const float* gz = (const float*)d_in[8];
    const float* bz = (const float*)d_in[9];
    const float* gy = (const float*)d_in[10];
    const float* by = (const float*)d_in[11];
    float* out = (float*)d_out;

    char* wsb = (char*)d_ws;
    unsigned* cnt = (unsigned*)wsb;                 wsb += 256;
    float* Z      = (float*)wsb;                    wsb += (size_t)B_ * H_ * 4;
    float* R2     = (float*)wsb;                    wsb += (size_t)B_ * H_ * 4;
    float* sums   = (float*)wsb;                    wsb += (size_t)RANK_ * 256 * 4;
    float* ysums  = (float*)wsb;                    wsb += 256 * 4;
    float* T      = (float*)wsb;                    wsb += (size_t)RANK_ * B_ * H_ * 4;
    __bf16* Zbf   = (__bf16*)wsb;                   wsb += (size_t)B_ * H_ * 2;
    __bf16* Pperm = (__bf16*)wsb;

    hipMemsetAsync(cnt, 0, 256, stream);
    k_mega<<<NBLK, 256, 0, stream>>>(X, W1, b1, W2, b2, W3, b3, P, gz, bz, gy, by,
                                     out, cnt, Z, R2, sums, ysums, T, Zbf, Pperm);
}

// Round 6
// 671.103 us; speedup vs baseline: 1.1277x; 1.1277x over previous
//
#include <hip/hip_runtime.h>

typedef __bf16 bf16x8 __attribute__((ext_vector_type(8)));
typedef float  floatx4 __attribute__((ext_vector_type(4)));

constexpr int B_    = 2048;
constexpr int NIN   = 256;
constexpr int H_    = 128;
constexpr int RANK_ = 8;
constexpr float EPS_ = 1e-5f;
constexpr int NBLK  = 512;          // 2 blocks/CU
constexpr int MT    = 32;           // rows per block
constexpr int SZS   = 36;           // sZin stride (floats), 16B-aligned rows

// Monotonic-counter grid barrier. 512 blocks co-resident via
// __launch_bounds__(256,2): LDS 19.5KB (<80KB/2), VGPR<=128.
// CRITICAL: poll with RELAXED agent load (no per-iteration cache invalidate);
// one release fence before arrive, one acquire fence after exit.
__device__ __forceinline__ void gsync(unsigned* cnt, unsigned target) {
    __syncthreads();
    if (threadIdx.x == 0) {
        __threadfence();   // release: publish this block's writes
        __hip_atomic_fetch_add(cnt, 1u, __ATOMIC_RELAXED, __HIP_MEMORY_SCOPE_AGENT);
        while (__hip_atomic_load(cnt, __ATOMIC_RELAXED, __HIP_MEMORY_SCOPE_AGENT) < target)
            __builtin_amdgcn_s_sleep(4);
        __threadfence();   // acquire: invalidate stale caches ONCE
    }
    __syncthreads();
}

__global__ __launch_bounds__(256, 2)
void k_mega(const float* __restrict__ X,  const float* __restrict__ W1, const float* __restrict__ b1,
            const float* __restrict__ W2, const float* __restrict__ b2,
            const float* __restrict__ W3, const float* __restrict__ b3,
            const float* __restrict__ P,  const float* __restrict__ gz, const float* __restrict__ bz,
            const float* __restrict__ gy, const float* __restrict__ by,
            float* __restrict__ out, unsigned* __restrict__ cnt,
            float* __restrict__ Z, float* __restrict__ R2,
            float* __restrict__ sums, float* __restrict__ ysums,
            float* __restrict__ T, __bf16* __restrict__ Zbf, __bf16* __restrict__ Pperm)
{
    __shared__ float smem[4864];     // 19,456 B
    const int bx = blockIdx.x, t = threadIdx.x;
    unsigned btgt = 0;

    // ===== phase 0: zero stats, in_proj (4 rows/blk), pconv (2 units/blk) =====
    if (bx < RANK_)       sums[bx * 256 + t] = 0.f;
    else if (bx == RANK_) ysums[t] = 0.f;

    {
        const int col = t & 127, half = t >> 7;
        for (int it = 0; it < 2; ++it) {
            const int row0 = bx * 4 + it * 2;
            smem[t]       = X[(size_t)row0       * NIN + t];
            smem[256 + t] = X[(size_t)(row0 + 1) * NIN + t];
            __syncthreads();
            float s1 = 0.f, s2 = 0.f;
            const float* sx = smem + half * 256;
#pragma unroll 8
            for (int i = 0; i < NIN; ++i) {
                s1 = fmaf(sx[i], W1[i * H_ + col], s1);
                s2 = fmaf(sx[i], W2[i * H_ + col], s2);
            }
            const int b = row0 + half;
            const float z = fmaxf(s1 + b1[col], 0.f);
            const float r = fmaxf(s2 + b2[col], 0.f);
            Z[(size_t)b * H_ + col]   = z;
            Zbf[(size_t)b * H_ + col] = (__bf16)z;
            R2[(size_t)b * H_ + col]  = r;
            __syncthreads();
        }
    }
    {
        const int s = t >> 6, Lp = t & 63, quad = Lp >> 4, lo = Lp & 15;
        for (int j = 0; j < 2; ++j) {
            const int u = bx * 2 + j, pr = u >> 7, p = u & 127;
            const float* Pp = P     + ((size_t)pr * H_ + p) * (H_ * H_);
            __bf16*      dp = Pperm + ((size_t)pr * H_ + p) * (H_ * H_);
#pragma unroll
            for (int c = 0; c < 8; ++c) {
                __bf16 v[8];
#pragma unroll
                for (int jj = 0; jj < 8; ++jj)
                    v[jj] = (__bf16)Pp[(s * 32 + quad * 8 + jj) * H_ + c * 16 + lo];
                *(bf16x8*)(dp + (((size_t)(s * 8 + c)) * 64 + Lp) * 8) = *(const bf16x8*)v;
            }
        }
    }
    btgt += NBLK; gsync(cnt, btgt);

    // ===== rank loop =====
    const int m = bx >> 3, kg = bx & 7, b0 = m * MT;
    const int w = t >> 6, L = t & 63, quad = L >> 4, lo = L & 15;
    const int sp = t & 127, rg = t >> 7;      // staging: col, row-parity

    // A-frags: rank-invariant Z rows
    bf16x8 A[2][4];
#pragma unroll
    for (int mt = 0; mt < 2; ++mt)
#pragma unroll
        for (int ks = 0; ks < 4; ++ks)
            A[mt][ks] = *(const bf16x8*)(Zbf + (size_t)(b0 + mt * 16 + lo) * H_ + ks * 32 + quad * 8);

    float Yacc[16];
#pragma unroll
    for (int i = 0; i < 16; ++i) Yacc[i] = 0.f;

    for (int r = 0; r < RANK_; ++r) {
        float* sAl = smem + 4608; float* sBe = smem + 4736;
        if (t < 128) {
            if (r == 0) { sAl[t] = 1.f; sBe[t] = 0.f; }
            else {
                const float s1 = sums[(r - 1) * 256 + t], s2 = sums[(r - 1) * 256 + 128 + t];
                const float mm = s1 * (1.f / B_);
                const float var = s2 * (1.f / B_) - mm * mm;
                const float a = rsqrtf(var + EPS_) * gz[t];
                sAl[t] = a; sBe[t] = bz[t] - mm * a;
            }
        }
        __syncthreads();
        {   // stage normalized Zi tile -> sZin[p][row]; fold into Yacc
            const float* prevT = (r == 0) ? Z : (T + (size_t)(r - 1) * B_ * H_);
            const float a = sAl[sp], be = sBe[sp];
#pragma unroll
            for (int i = 0; i < 16; ++i) {
                const int row = rg + 2 * i;
                const float zin = fmaf(prevT[(size_t)(b0 + row) * H_ + sp], a, be);
                smem[sp * SZS + row] = zin;
                if (r >= 1) Yacc[i] += zin;
            }
        }
        __syncthreads();

        floatx4 acc[2];
        acc[0] = (floatx4){0.f, 0.f, 0.f, 0.f};
        acc[1] = (floatx4){0.f, 0.f, 0.f, 0.f};
        const bf16x8* Pb = (const bf16x8*)(Pperm + (size_t)r * H_ * H_ * H_);
        for (int pp = 0; pp < 32; ++pp) {
            const int p = pp * 4 + w;
            bf16x8 Bf[4];
#pragma unroll
            for (int s = 0; s < 4; ++s)
                Bf[s] = Pb[((size_t)(p * 4 + s) * 8 + kg) * 64 + L];
            floatx4 S[2];
            S[0] = (floatx4){0.f, 0.f, 0.f, 0.f};
            S[1] = (floatx4){0.f, 0.f, 0.f, 0.f};
#pragma unroll
            for (int ks = 0; ks < 4; ++ks)
#pragma unroll
                for (int mt = 0; mt < 2; ++mt)
                    S[mt] = __builtin_amdgcn_mfma_f32_16x16x32_bf16(A[mt][ks], Bf[ks], S[mt], 0, 0, 0);
#pragma unroll
            for (int mt = 0; mt < 2; ++mt) {
                const floatx4 zi = *(const floatx4*)&smem[p * SZS + mt * 16 + quad * 4];
                acc[mt] += zi * S[mt];
            }
        }
        __syncthreads();                  // sZin dead; reuse for reduce
#pragma unroll
        for (int mt = 0; mt < 2; ++mt)
#pragma unroll
            for (int i = 0; i < 4; ++i)
                smem[w * 512 + (mt * 4 + i) * 64 + L] = acc[mt][i];
        if (t < 32) smem[2048 + t] = 0.f;
        __syncthreads();

        float* Tr = T + (size_t)r * B_ * H_;
        float cs = 0.f, cs2 = 0.f;
#pragma unroll
        for (int k2 = 0; k2 < 2; ++k2) {
            const int e = t + 256 * k2;
            const float v = smem[e] + smem[512 + e] + smem[1024 + e] + smem[1536 + e];
            const int j = e >> 6, L2 = e & 63;
            const int row = b0 + (j >> 2) * 16 + (L2 >> 4) * 4 + (j & 3);
            const int col = kg * 16 + (L2 & 15);
            Tr[(size_t)row * H_ + col] = v;
            cs += v; cs2 += v * v;
        }
        cs  += __shfl_xor(cs, 16);  cs  += __shfl_xor(cs, 32);
        cs2 += __shfl_xor(cs2, 16); cs2 += __shfl_xor(cs2, 32);
        if (L < 16) { atomicAdd(&smem[2048 + L], cs); atomicAdd(&smem[2064 + L], cs2); }
        __syncthreads();
        if (t < 16)      atomicAdd(&sums[r * 256 + kg * 16 + t],        smem[2048 + t]);
        else if (t < 32) atomicAdd(&sums[r * 256 + 128 + kg * 16 + t - 16], smem[2048 + t]);

        btgt += NBLK; gsync(cnt, btgt);
    }

    // ===== final: Zin_7 into Yacc, Y stats =====
    {
        float* sAl = smem + 4608; float* sBe = smem + 4736;
        if (t < 128) {
            const float s1 = sums[7 * 256 + t], s2 = sums[7 * 256 + 128 + t];
            const float mm = s1 * (1.f / B_);
            const float var = s2 * (1.f / B_) - mm * mm;
            const float a = rsqrtf(var + EPS_) * gz[t];
            sAl[t] = a; sBe[t] = bz[t] - mm * a;
        }
        if (t < 256) { smem[t] = 0.f; }
        __syncthreads();
        const float a = sAl[sp], be = sBe[sp];
        const float* T7 = T + (size_t)7 * B_ * H_;
        float ps = 0.f, ps2 = 0.f;
#pragma unroll
        for (int i = 0; i < 16; ++i) {
            const int row = rg + 2 * i;
            const float zin = fmaf(T7[(size_t)(b0 + row) * H_ + sp], a, be);
            const float y = (Yacc[i] + zin) * (1.f / RANK_);
            Yacc[i] = y;
            ps += y; ps2 += y * y;
        }
        atomicAdd(&smem[sp], ps);
        atomicAdd(&smem[128 + sp], ps2);
        __syncthreads();
        if (kg == 0 && t < 128) {
            atomicAdd(&ysums[t],       smem[t]);
            atomicAdd(&ysums[128 + t], smem[128 + t]);
        }
    }
    btgt += NBLK; gsync(cnt, btgt);

    // ===== F2: out = relu(relu(BN(Y)@W3 + b3) + R2), block cols kg*16.. =====
    {
        const float mm = ysums[sp] * (1.f / B_);
        const float var = ysums[128 + sp] * (1.f / B_) - mm * mm;
        const float ay = rsqrtf(var + EPS_) * gy[sp];
        const float bb = by[sp] - mm * ay;
#pragma unroll
        for (int i = 0; i < 16; ++i)
            smem[(rg + 2 * i) * 129 + sp] = fmaf(Yacc[i], ay, bb);
        __syncthreads();
        const int orow = t >> 4;
        const int ocol = kg * 16 + (t & 15);
        for (int rr = orow; rr < MT; rr += 16) {
            float s = 0.f;
            const float* sy = smem + rr * 129;
#pragma unroll 8
            for (int h = 0; h < H_; ++h)
                s = fmaf(sy[h], W3[h * H_ + ocol], s);
            const size_t gi = (size_t)(b0 + rr) * H_ + ocol;
            out[gi] = fmaxf(fmaxf(s + b3[ocol], 0.f) + R2[gi], 0.f);
        }
    }
}

// ---------------------------------------------------------------------------
extern "C" void kernel_launch(void* const* d_in, const int* in_sizes, int n_in,
                              void* d_out, int out_size, void* d_ws, size_t ws_size,
                              hipStream_t stream) {
    const float* X  = (const float*)d_in[0];
    const float* W1 = (const float*)d_in[1];
    const float* b1 = (const float*)d_in[2];
    const float* W2 = (const float*)d_in[3];
    const float* b2 = (const float*)d_in[4];
    const float* W3 = (const float*)d_in[5];
    const float* b3 = (const float*)d_in[6];
    const float* P  = (const float*)d_in[7];
    const float* gz = (const float*)d_in[8];
    const float* bz = (const float*)d_in[9];
    const float* gy = (const float*)d_in[10];
    const float* by = (const float*)d_in[11];
    float* out = (float*)d_out;

    char* wsb = (char*)d_ws;
    unsigned* cnt = (unsigned*)wsb;                 wsb += 256;
    float* Z      = (float*)wsb;                    wsb += (size_t)B_ * H_ * 4;
    float* R2     = (float*)wsb;                    wsb += (size_t)B_ * H_ * 4;
    float* sums   = (float*)wsb;                    wsb += (size_t)RANK_ * 256 * 4;
    float* ysums  = (float*)wsb;                    wsb += 256 * 4;
    float* T      = (float*)wsb;                    wsb += (size_t)RANK_ * B_ * H_ * 4;
    __bf16* Zbf   = (__bf16*)wsb;                   wsb += (size_t)B_ * H_ * 2;
    __bf16* Pperm = (__bf16*)wsb;

    hipMemsetAsync(cnt, 0, 256, stream);
    k_mega<<<NBLK, 256, 0, stream>>>(X, W1, b1, W2, b2, W3, b3, P, gz, bz, gy, by,
                                     out, cnt, Z, R2, sums, ysums, T, Zbf, Pperm);
}

// Round 7
// 334.482 us; speedup vs baseline: 2.2625x; 2.0064x over previous
//
#include <hip/hip_runtime.h>

typedef __bf16 bf16x8 __attribute__((ext_vector_type(8)));
typedef float  floatx4 __attribute__((ext_vector_type(4)));

constexpr int B_    = 2048;
constexpr int NIN   = 256;
constexpr int H_    = 128;
constexpr int RANK_ = 8;
constexpr float EPS_ = 1e-5f;
constexpr int MT    = 32;           // rows per rank-block
constexpr int SZS   = 36;           // sZin stride (floats)

// ---------------------------------------------------------------------------
// HEAD: zero stats (9*256), in_proj (blocks 0..511, 4 rows each), pconv
// (all 1024 blocks, 1 p-unit each). Grid 1024 x 256.
__global__ __launch_bounds__(256)
void k_head(const float* __restrict__ X,
            const float* __restrict__ W1, const float* __restrict__ b1,
            const float* __restrict__ W2, const float* __restrict__ b2,
            const float* __restrict__ P,
            float* __restrict__ Z, float* __restrict__ R2, __bf16* __restrict__ Zbf,
            __bf16* __restrict__ Pperm, float* __restrict__ stats /* 9*256 */) {
    __shared__ float smem[512];
    const int bx = blockIdx.x, t = threadIdx.x;

    if (bx < RANK_ + 1) stats[bx * 256 + t] = 0.f;

    if (bx < 512) {   // in_proj rows bx*4 .. +4
        const int col = t & 127, half = t >> 7;
        for (int it = 0; it < 2; ++it) {
            const int row0 = bx * 4 + it * 2;
            smem[t]       = X[(size_t)row0       * NIN + t];
            smem[256 + t] = X[(size_t)(row0 + 1) * NIN + t];
            __syncthreads();
            float s1 = 0.f, s2 = 0.f;
            const float* sx = smem + half * 256;
#pragma unroll 8
            for (int i = 0; i < NIN; ++i) {
                s1 = fmaf(sx[i], W1[i * H_ + col], s1);
                s2 = fmaf(sx[i], W2[i * H_ + col], s2);
            }
            const int b = row0 + half;
            const float z = fmaxf(s1 + b1[col], 0.f);
            const float r = fmaxf(s2 + b2[col], 0.f);
            Z[(size_t)b * H_ + col]   = z;
            Zbf[(size_t)b * H_ + col] = (__bf16)z;
            R2[(size_t)b * H_ + col]  = r;
            __syncthreads();
        }
    }
    {   // pconv: unit u = bx (8 ranks x 128 p), B-frag order
        const int s = t >> 6, Lp = t & 63, quad = Lp >> 4, lo = Lp & 15;
        const int pr = bx >> 7, p = bx & 127;
        const float* Pp = P     + ((size_t)pr * H_ + p) * (H_ * H_);
        __bf16*      dp = Pperm + ((size_t)pr * H_ + p) * (H_ * H_);
#pragma unroll
        for (int c = 0; c < 8; ++c) {
            __bf16 v[8];
#pragma unroll
            for (int jj = 0; jj < 8; ++jj)
                v[jj] = (__bf16)Pp[(s * 32 + quad * 8 + jj) * H_ + c * 16 + lo];
            *(bf16x8*)(dp + (((size_t)(s * 8 + c)) * 64 + Lp) * 8) = *(const bf16x8*)v;
        }
    }
}

// ---------------------------------------------------------------------------
// RANK r: T_r[b,k] = sum_p BNprev(prevT)[b,p] * (Zbf @ P_r[p])[b,k]; stats_r.
// BN of the previous rank folded into the staging read (identity if first).
// Grid (64 m, 8 kg) x 256; 2 blocks/CU.
__global__ __launch_bounds__(256, 2)
void k_rank(const __bf16* __restrict__ Pr, const __bf16* __restrict__ Zbf,
            const float* __restrict__ prevT, const float* __restrict__ prevStats,
            const float* __restrict__ gz, const float* __restrict__ bz,
            float* __restrict__ T, float* __restrict__ stats, const int first) {
    __shared__ float smem[4864];     // sZin[128][36] + sAl[128] + sBe[128]
    const int m = blockIdx.x, kg = blockIdx.y, b0 = m * MT;
    const int t = threadIdx.x;
    const int w = t >> 6, L = t & 63, quad = L >> 4, lo = L & 15;
    const int sp = t & 127, rg = t >> 7;

    float* sAl = smem + 4608; float* sBe = smem + 4736;
    if (t < 128) {
        if (first) { sAl[t] = 1.f; sBe[t] = 0.f; }
        else {
            const float s1 = prevStats[t], s2 = prevStats[128 + t];
            const float mm = s1 * (1.f / B_);
            const float var = s2 * (1.f / B_) - mm * mm;
            const float a = rsqrtf(var + EPS_) * gz[t];
            sAl[t] = a; sBe[t] = bz[t] - mm * a;
        }
    }
    // A-frags (rank-invariant Z rows) — issue while sAl/sBe settle
    bf16x8 A[2][4];
#pragma unroll
    for (int mt = 0; mt < 2; ++mt)
#pragma unroll
        for (int ks = 0; ks < 4; ++ks)
            A[mt][ks] = *(const bf16x8*)(Zbf + (size_t)(b0 + mt * 16 + lo) * H_ + ks * 32 + quad * 8);
    __syncthreads();
    {   // stage normalized Zin tile -> sZin[p][row]
        const float a = sAl[sp], be = sBe[sp];
#pragma unroll
        for (int i = 0; i < 16; ++i) {
            const int row = rg + 2 * i;
            smem[sp * SZS + row] = fmaf(prevT[(size_t)(b0 + row) * H_ + sp], a, be);
        }
    }
    __syncthreads();

    floatx4 acc[2];
    acc[0] = (floatx4){0.f, 0.f, 0.f, 0.f};
    acc[1] = (floatx4){0.f, 0.f, 0.f, 0.f};
    const bf16x8* Pb = (const bf16x8*)Pr;
    for (int pp = 0; pp < 32; ++pp) {
        const int p = pp * 4 + w;
        bf16x8 Bf[4];
#pragma unroll
        for (int s = 0; s < 4; ++s)
            Bf[s] = Pb[((size_t)(p * 4 + s) * 8 + kg) * 64 + L];
        floatx4 S[2];
        S[0] = (floatx4){0.f, 0.f, 0.f, 0.f};
        S[1] = (floatx4){0.f, 0.f, 0.f, 0.f};
#pragma unroll
        for (int ks = 0; ks < 4; ++ks)
#pragma unroll
            for (int mt = 0; mt < 2; ++mt)
                S[mt] = __builtin_amdgcn_mfma_f32_16x16x32_bf16(A[mt][ks], Bf[ks], S[mt], 0, 0, 0);
#pragma unroll
        for (int mt = 0; mt < 2; ++mt) {
            const floatx4 zi = *(const floatx4*)&smem[p * SZS + mt * 16 + quad * 4];
            acc[mt] += zi * S[mt];
        }
    }
    __syncthreads();                  // sZin dead; reuse for cross-wave reduce
#pragma unroll
    for (int mt = 0; mt < 2; ++mt)
#pragma unroll
        for (int i = 0; i < 4; ++i)
            smem[w * 512 + (mt * 4 + i) * 64 + L] = acc[mt][i];
    if (t < 32) smem[2048 + t] = 0.f;
    __syncthreads();

    float cs = 0.f, cs2 = 0.f;
#pragma unroll
    for (int k2 = 0; k2 < 2; ++k2) {
        const int e = t + 256 * k2;
        const float v = smem[e] + smem[512 + e] + smem[1024 + e] + smem[1536 + e];
        const int j = e >> 6, L2 = e & 63;
        const int row = b0 + (j >> 2) * 16 + (L2 >> 4) * 4 + (j & 3);
        const int col = kg * 16 + (L2 & 15);
        T[(size_t)row * H_ + col] = v;
        cs += v; cs2 += v * v;
    }
    cs  += __shfl_xor(cs, 16);  cs  += __shfl_xor(cs, 32);
    cs2 += __shfl_xor(cs2, 16); cs2 += __shfl_xor(cs2, 32);
    if (L < 16) { atomicAdd(&smem[2048 + L], cs); atomicAdd(&smem[2064 + L], cs2); }
    __syncthreads();
    if (t < 16)      atomicAdd(&stats[kg * 16 + t],            smem[2048 + t]);
    else if (t < 32) atomicAdd(&stats[128 + kg * 16 + t - 16], smem[2048 + t]);
}

// ---------------------------------------------------------------------------
// Y = (1/8) sum_r BN_r(T_r); ystats. Grid 64 x 256.
__global__ __launch_bounds__(256)
void k_y(const float* __restrict__ T, const float* __restrict__ sums,
         const float* __restrict__ gz, const float* __restrict__ bz,
         float* __restrict__ Y, float* __restrict__ ysums) {
    __shared__ float al[1024], be[1024], red[256];
    const int bx = blockIdx.x, t = threadIdx.x;
    for (int e = t; e < 1024; e += 256) {
        const int rr = e >> 7, k = e & 127;
        const float s1 = sums[rr * 256 + k], s2 = sums[rr * 256 + 128 + k];
        const float mm = s1 * (1.f / B_);
        const float var = s2 * (1.f / B_) - mm * mm;
        const float a = rsqrtf(var + EPS_) * gz[k];
        al[e] = a; be[e] = bz[k] - mm * a;
    }
    red[t] = 0.f;
    __syncthreads();
    const int col = t & 127, half = t >> 7;
    float ps = 0.f, ps2 = 0.f;
    for (int i = 0; i < 16; ++i) {
        const int b = bx * 32 + half + 2 * i;
        float y = 0.f;
#pragma unroll
        for (int rr = 0; rr < 8; ++rr)
            y += fmaf(T[(size_t)rr * B_ * H_ + (size_t)b * H_ + col],
                      al[rr * 128 + col], be[rr * 128 + col]);
        y *= (1.f / RANK_);
        Y[(size_t)b * H_ + col] = y;
        ps += y; ps2 += y * y;
    }
    atomicAdd(&red[col], half == 0 ? ps : 0.f);   // split to reduce collisions
    atomicAdd(&red[128 + col], half == 0 ? ps2 : 0.f);
    __syncthreads();
    atomicAdd(&red[col],       half == 1 ? ps : 0.f);
    atomicAdd(&red[128 + col], half == 1 ? ps2 : 0.f);
    __syncthreads();
    if (t < 128) {
        atomicAdd(&ysums[t],       red[t]);
        atomicAdd(&ysums[128 + t], red[128 + t]);
    }
}

// ---------------------------------------------------------------------------
// out = relu(relu(BN(Y)@W3 + b3) + R2). Grid B_ x 128.
__global__ void k_out(const float* __restrict__ Y, const float* __restrict__ ystats,
                      const float* __restrict__ gy, const float* __restrict__ by,
                      const float* __restrict__ W3, const float* __restrict__ b3,
                      const float* __restrict__ R2, float* __restrict__ out) {
    __shared__ float sy[H_];
    const int b = blockIdx.x, t = threadIdx.x;
    const float m  = ystats[t] * (1.f / B_);
    const float v  = ystats[128 + t] * (1.f / B_) - m * m;
    const float rs = rsqrtf(v + EPS_);
    sy[t] = (Y[(size_t)b * H_ + t] - m) * rs * gy[t] + by[t];
    __syncthreads();
    float s = 0.f;
#pragma unroll 8
    for (int h = 0; h < H_; ++h)
        s = fmaf(sy[h], W3[h * H_ + t], s);
    const float r = fmaxf(s + b3[t], 0.f) + R2[(size_t)b * H_ + t];
    out[(size_t)b * H_ + t] = fmaxf(r, 0.f);
}

// ---------------------------------------------------------------------------
extern "C" void kernel_launch(void* const* d_in, const int* in_sizes, int n_in,
                              void* d_out, int out_size, void* d_ws, size_t ws_size,
                              hipStream_t stream) {
    const float* X  = (const float*)d_in[0];
    const float* W1 = (const float*)d_in[1];
    const float* b1 = (const float*)d_in[2];
    const float* W2 = (const float*)d_in[3];
    const float* b2 = (const float*)d_in[4];
    const float* W3 = (const float*)d_in[5];
    const float* b3 = (const float*)d_in[6];
    const float* P  = (const float*)d_in[7];
    const float* gz = (const float*)d_in[8];
    const float* bz = (const float*)d_in[9];
    const float* gy = (const float*)d_in[10];
    const float* by = (const float*)d_in[11];
    float* out = (float*)d_out;

    const size_t rankElems = (size_t)H_ * H_ * H_;

    char* wsb = (char*)d_ws;
    float* Z      = (float*)wsb;   wsb += (size_t)B_ * H_ * 4;
    float* R2     = (float*)wsb;   wsb += (size_t)B_ * H_ * 4;
    float* Y      = (float*)wsb;   wsb += (size_t)B_ * H_ * 4;
    float* stats  = (float*)wsb;   wsb += (size_t)(RANK_ + 1) * 256 * 4;  // sums | ysums
    float* T      = (float*)wsb;   wsb += (size_t)RANK_ * B_ * H_ * 4;
    __bf16* Zbf   = (__bf16*)wsb;  wsb += (size_t)B_ * H_ * 2;
    __bf16* Pperm = (__bf16*)wsb;

    float* ysums = stats + RANK_ * 256;

    k_head<<<1024, 256, 0, stream>>>(X, W1, b1, W2, b2, P, Z, R2, Zbf, Pperm, stats);

    for (int r = 0; r < RANK_; ++r) {
        const float* prevT = (r == 0) ? Z : (T + (size_t)(r - 1) * B_ * H_);
        const float* prevS = (r == 0) ? stats : (stats + (r - 1) * 256);
        k_rank<<<dim3(64, 8), 256, 0, stream>>>(Pperm + (size_t)r * rankElems, Zbf,
                                                prevT, prevS, gz, bz,
                                                T + (size_t)r * B_ * H_, stats + r * 256,
                                                r == 0 ? 1 : 0);
    }

    k_y<<<64, 256, 0, stream>>>(T, stats, gz, bz, Y, ysums);
    k_out<<<B_, H_, 0, stream>>>(Y, ysums, gy, by, W3, b3, R2, out);
}